// Round 4
// baseline (708.017 us; speedup 1.0000x reference)
//
#include <hip/hip_runtime.h>
#include <cstdint>

// InstantNGP hash-grid encoder, MI355X, v4.
// D=3, L=16, F=2, N_MIN=16, PLS=2 -> scale_l = 16*2^l - 1, res_l = 16*2^l.
// Levels 0..2 dense (mod provably no-op), levels 3..15 hashed, hmap=2^19,
// each hashed table = 4 MB = one XCD L2.
// v3 lessons (rocprof): level kernels are bound by random 64B-line service
// (~4.5 lines/pt, ~98 G lines/s chip-wide); 2x MLP + fewer load instrs moved
// nothing. Final kernel write-amp fixed (125 MB) but only 2.75 TB/s (LDS
// occupancy 34%).
// v4: (1) one mega-kernel, zone = blockIdx/NB: zone 0 = dense levels 0..2,
// zones 1..13 = hashed levels 3..15 (block-order => temporal L2 affinity,
// no inter-dispatch bubbles); (2) non-temporal loads/stores for all stream
// traffic so tables stay L2-resident; (3) final transpose without LDS:
// thread -> one out float4, wave reads whole 64B lines of ws (8 consecutive
// points x 16 rows), full occupancy.

static constexpr uint32_t kOff[17] = {
    0u, 4913u, 40850u, 315475u, 839763u, 1364051u, 1888339u, 2412627u,
    2936915u, 3461203u, 3985491u, 4509779u, 5034067u, 5558355u, 6082643u,
    6606931u, 7131219u};
// kOff[l] for l>=3 is 315475 + (l-3)*524288 (each hashed table 2^19 entries).

static constexpr uint32_t P1 = 2654435761u;
static constexpr uint32_t P2 = 805459861u;

// 16B vector with 8B alignment (table pair-loads never straddle a 64B line).
typedef float f4a8 __attribute__((ext_vector_type(4), aligned(8)));
typedef float v2f __attribute__((ext_vector_type(2)));
typedef float v4f __attribute__((ext_vector_type(4)));

__device__ __forceinline__ float2 ntload2(const float2* p) {
  v2f t = __builtin_nontemporal_load((const v2f*)p);
  return make_float2(t[0], t[1]);
}
__device__ __forceinline__ void ntstore2(float2* p, float a, float b) {
  v2f t;
  t[0] = a;
  t[1] = b;
  __builtin_nontemporal_store(t, (v2f*)p);
}
__device__ __forceinline__ void ntstore4(float4* p, float a, float b, float c,
                                         float d) {
  v4f t;
  t[0] = a;
  t[1] = b;
  t[2] = c;
  t[3] = d;
  __builtin_nontemporal_store(t, (v4f*)p);
}

__device__ __forceinline__ float to_unit(float v) {
  // x = (in + 1) / 2 ; *0.5 exact, matches reference
  return __fmul_rn(__fadd_rn(v, 1.0f), 0.5f);
}

// pos = x*scale + 0.5 with separate mul/add rounding (match reference).
__device__ __forceinline__ void pos_decomp_rt(float x0, float x1, float x2,
                                              float scale, uint32_t& i0,
                                              uint32_t& i1, uint32_t& i2,
                                              float& f0, float& f1, float& f2) {
  float p0 = __fadd_rn(__fmul_rn(x0, scale), 0.5f);
  float p1 = __fadd_rn(__fmul_rn(x1, scale), 0.5f);
  float p2 = __fadd_rn(__fmul_rn(x2, scale), 0.5f);
  float g0 = floorf(p0), g1 = floorf(p1), g2 = floorf(p2);
  f0 = __fsub_rn(p0, g0);
  f1 = __fsub_rn(p1, g1);
  f2 = __fsub_rn(p2, g2);
  i0 = (uint32_t)g0;
  i1 = (uint32_t)g1;
  i2 = (uint32_t)g2;
}

// Hashed level, runtime scale/table-base (identical for all levels >= 3:
// mask 2^19-1, primes fixed). Reference corner order and fp op order kept.
__device__ __forceinline__ void hashed_accum_rt(float x0, float x1, float x2,
                                                float scale,
                                                const float2* __restrict__ t2,
                                                float& A0, float& A1) {
  constexpr uint32_t mask = 0x7FFFFu;  // hmap = 2^19
  uint32_t i0, i1, i2;
  float f0, f1, f2;
  pos_decomp_rt(x0, x1, x2, scale, i0, i1, i2, f0, f1, f2);

  const float w0l = __fsub_rn(1.0f, f0), w0h = f0;
  const float w1v[2] = {__fsub_rn(1.0f, f1), f1};
  const float w2v[2] = {__fsub_rn(1.0f, f2), f2};
  uint32_t h1v[2], h2v[2];
  h1v[0] = i1 * P1;
  h1v[1] = h1v[0] + P1;
  h2v[0] = i2 * P2;
  h2v[1] = h2v[0] + P2;

  const bool odd = (i0 & 1u) != 0u;
  float acc0 = A0, acc1 = A1;
#pragma unroll
  for (int b2 = 0; b2 < 2; ++b2) {
#pragma unroll
    for (int b1 = 0; b1 < 2; ++b1) {
      const uint32_t ex = h1v[b1] ^ h2v[b2];
      const uint32_t ilo = (i0 ^ ex) & mask;
      // one 16B load covers entries {ilo&~1, ilo|1}
      const f4a8 v = *(const f4a8*)(t2 + (ilo & ~1u));
      const bool hs = (ilo & 1u) != 0u;
      float eL0 = hs ? v.z : v.x;
      float eL1 = hs ? v.w : v.y;
      float eH0 = hs ? v.x : v.z;  // valid when i0 even (ihi == ilo^1)
      float eH1 = hs ? v.y : v.w;
      if (odd) {
        const uint32_t ihi = ((i0 + 1u) ^ ex) & mask;
        const float2 e = t2[ihi];
        eH0 = e.x;
        eH1 = e.y;
      }
      const float wl = __fmul_rn(__fmul_rn(w0l, w1v[b1]), w2v[b2]);
      const float wh = __fmul_rn(__fmul_rn(w0h, w1v[b1]), w2v[b2]);
      acc0 = __fadd_rn(acc0, __fmul_rn(wl, eL0));
      acc1 = __fadd_rn(acc1, __fmul_rn(wl, eL1));
      acc0 = __fadd_rn(acc0, __fmul_rn(wh, eH0));
      acc1 = __fadd_rn(acc1, __fmul_rn(wh, eH1));
    }
  }
  A0 = acc0;
  A1 = acc1;
}

// Dense level (LV < 3): corner pair always adjacent -> one 16B load.
template <int LV>
__device__ __forceinline__ void dense_accum(float x0, float x1, float x2,
                                            const float* __restrict__ embf,
                                            float& A0, float& A1) {
  static_assert(LV < 3, "");
  constexpr uint32_t res = 16u << LV;
  constexpr uint32_t off = kOff[LV];
  constexpr uint32_t s1 = res + 1u, s2 = s1 * s1;
  constexpr float scale = (float)res - 1.0f;
  uint32_t i0, i1, i2;
  float f0, f1, f2;
  pos_decomp_rt(x0, x1, x2, scale, i0, i1, i2, f0, f1, f2);

  const float w0l = __fsub_rn(1.0f, f0), w0h = f0;
  const float w1v[2] = {__fsub_rn(1.0f, f1), f1};
  const float w2v[2] = {__fsub_rn(1.0f, f2), f2};
  const uint32_t base = i0 + i1 * s1 + i2 * s2;
  const float2* t2 = (const float2*)embf + off;

  float acc0 = A0, acc1 = A1;
#pragma unroll
  for (int b2 = 0; b2 < 2; ++b2) {
#pragma unroll
    for (int b1 = 0; b1 < 2; ++b1) {
      const uint32_t idx = base + (b1 ? s1 : 0u) + (b2 ? s2 : 0u);
      const f4a8 v = *(const f4a8*)(t2 + idx);  // {e[idx], e[idx+1]}
      const float wl = __fmul_rn(__fmul_rn(w0l, w1v[b1]), w2v[b2]);
      const float wh = __fmul_rn(__fmul_rn(w0h, w1v[b1]), w2v[b2]);
      acc0 = __fadd_rn(acc0, __fmul_rn(wl, v.x));
      acc1 = __fadd_rn(acc1, __fmul_rn(wl, v.y));
      acc0 = __fadd_rn(acc0, __fmul_rn(wh, v.z));
      acc1 = __fadd_rn(acc1, __fmul_rn(wh, v.w));
    }
  }
  A0 = acc0;
  A1 = acc1;
}

// --------------------------- mega gather kernel ---------------------------
// zone 0: dense levels 0..2; zone z in 1..13: hashed level z+2.
// 2 points/thread; ws layout [16][B] float2.

__global__ __launch_bounds__(256) void mega_kernel(
    const float* __restrict__ in, const float* __restrict__ embf,
    float2* __restrict__ ws, int B, int NB) {
  const int zone = blockIdx.x / NB;
  const int q = (blockIdx.x - zone * NB) * 256 + threadIdx.x;
  const int p0 = q << 1;
  if (p0 >= B) return;
  const bool hasB = (p0 + 1) < B;

  float xA0, xA1, xA2, xB0 = 0.f, xB1 = 0.f, xB2 = 0.f;
  if (hasB) {
    const float2* in2 = (const float2*)in;
    const size_t b3 = (size_t)q * 3;
    const float2 u0 = ntload2(in2 + b3);
    const float2 u1 = ntload2(in2 + b3 + 1);
    const float2 u2 = ntload2(in2 + b3 + 2);
    xA0 = to_unit(u0.x);
    xA1 = to_unit(u0.y);
    xA2 = to_unit(u1.x);
    xB0 = to_unit(u1.y);
    xB1 = to_unit(u2.x);
    xB2 = to_unit(u2.y);
  } else {  // last point when B odd: avoid reading past in[]
    xA0 = to_unit(in[(size_t)p0 * 3 + 0]);
    xA1 = to_unit(in[(size_t)p0 * 3 + 1]);
    xA2 = to_unit(in[(size_t)p0 * 3 + 2]);
  }
  const bool pair4 = hasB && ((B & 1) == 0);  // 16B-aligned float4 ws store

  if (zone == 0) {
    float a0, a1, b0, b1;
#define DO_DENSE(LV)                                              \
  a0 = a1 = b0 = b1 = 0.0f;                                       \
  dense_accum<LV>(xA0, xA1, xA2, embf, a0, a1);                   \
  if (hasB) dense_accum<LV>(xB0, xB1, xB2, embf, b0, b1);         \
  {                                                               \
    float2* wsl = ws + (size_t)LV * B;                            \
    if (pair4)                                                    \
      ntstore4((float4*)(wsl + p0), a0, a1, b0, b1);              \
    else {                                                        \
      ntstore2(wsl + p0, a0, a1);                                 \
      if (hasB) ntstore2(wsl + p0 + 1, b0, b1);                   \
    }                                                             \
  }
    DO_DENSE(0)
    DO_DENSE(1)
    DO_DENSE(2)
#undef DO_DENSE
  } else {
    const int level = zone + 2;  // 3..15
    const float scale = (float)(int)((16u << level) - 1u);
    const float2* t2 =
        (const float2*)embf + (315475u + (uint32_t)(level - 3) * 524288u);
    float2* wsl = ws + (size_t)level * B;

    float a0 = 0.0f, a1 = 0.0f;
    hashed_accum_rt(xA0, xA1, xA2, scale, t2, a0, a1);
    if (pair4) {
      float b0 = 0.0f, b1 = 0.0f;
      hashed_accum_rt(xB0, xB1, xB2, scale, t2, b0, b1);
      ntstore4((float4*)(wsl + p0), a0, a1, b0, b1);
    } else {
      ntstore2(wsl + p0, a0, a1);
      if (hasB) {
        float b0 = 0.0f, b1 = 0.0f;
        hashed_accum_rt(xB0, xB1, xB2, scale, t2, b0, b1);
        ntstore2(wsl + p0 + 1, b0, b1);
      }
    }
  }
}

// ------------------------- full-line transpose -------------------------
// thread -> one out float4 (point p = g>>3, quad j = g&7, levels 2j,2j+1).
// Per wave: 8 consecutive points x 16 ws rows = whole 64B lines both sides.

__global__ __launch_bounds__(256) void transpose_kernel(
    const float2* __restrict__ ws, float4* __restrict__ out4, size_t n4,
    int B) {
  const size_t g = (size_t)blockIdx.x * 256 + threadIdx.x;
  if (g >= n4) return;
  const int p = (int)(g >> 3);
  const int j = (int)(g & 7);
  const float2 e0 = ntload2(ws + (size_t)(2 * j) * B + p);
  const float2 e1 = ntload2(ws + (size_t)(2 * j + 1) * B + p);
  ntstore4(out4 + g, e0.x, e0.y, e1.x, e1.y);
}

// ---------------- fallback (ws too small): 8 levels/kernel ----------------

template <int LV>
__device__ __forceinline__ void any_accum(float x0, float x1, float x2,
                                          const float* __restrict__ embf,
                                          float& A0, float& A1) {
  if constexpr (LV < 3) {
    dense_accum<LV>(x0, x1, x2, embf, A0, A1);
  } else {
    constexpr float scale = (float)(16u << LV) - 1.0f;
    const float2* t2 = (const float2*)embf + kOff[LV];
    hashed_accum_rt(x0, x1, x2, scale, t2, A0, A1);
  }
}

template <int LBASE>
__global__ __launch_bounds__(256) void grid_enc_kernel(
    const float* __restrict__ in, const float* __restrict__ embf,
    float* __restrict__ out, int B) {
  const int p = blockIdx.x * 256 + threadIdx.x;
  if (p >= B) return;
  const float x0 = to_unit(in[(size_t)p * 3 + 0]);
  const float x1 = to_unit(in[(size_t)p * 3 + 1]);
  const float x2 = to_unit(in[(size_t)p * 3 + 2]);

  float a[16];
#pragma unroll
  for (int i = 0; i < 16; ++i) a[i] = 0.0f;

  any_accum<LBASE + 0>(x0, x1, x2, embf, a[0], a[1]);
  any_accum<LBASE + 1>(x0, x1, x2, embf, a[2], a[3]);
  any_accum<LBASE + 2>(x0, x1, x2, embf, a[4], a[5]);
  any_accum<LBASE + 3>(x0, x1, x2, embf, a[6], a[7]);
  any_accum<LBASE + 4>(x0, x1, x2, embf, a[8], a[9]);
  any_accum<LBASE + 5>(x0, x1, x2, embf, a[10], a[11]);
  any_accum<LBASE + 6>(x0, x1, x2, embf, a[12], a[13]);
  any_accum<LBASE + 7>(x0, x1, x2, embf, a[14], a[15]);

  float4* __restrict__ o = (float4*)(out + (size_t)p * 32 + LBASE * 2);
  o[0] = make_float4(a[0], a[1], a[2], a[3]);
  o[1] = make_float4(a[4], a[5], a[6], a[7]);
  o[2] = make_float4(a[8], a[9], a[10], a[11]);
  o[3] = make_float4(a[12], a[13], a[14], a[15]);
}

extern "C" void kernel_launch(void* const* d_in, const int* in_sizes, int n_in,
                              void* d_out, int out_size, void* d_ws,
                              size_t ws_size, hipStream_t stream) {
  const float* in = (const float*)d_in[0];
  const float* emb = (const float*)d_in[1];
  float* out = (float*)d_out;
  const int B = in_sizes[0] / 3;
  const size_t ws_needed = (size_t)16 * (size_t)B * sizeof(float2);

  if (ws_size >= ws_needed) {
    float2* ws = (float2*)d_ws;
    const int NB = ((B + 1) / 2 + 255) / 256;  // blocks per zone
    mega_kernel<<<NB * 14, 256, 0, stream>>>(in, emb, ws, B, NB);
    const size_t n4 = (size_t)B * 8;  // out float4 count
    const int tb = (int)((n4 + 255) / 256);
    transpose_kernel<<<tb, 256, 0, stream>>>(ws, (float4*)out, n4, B);
  } else {
    const int blocksP = (B + 255) / 256;
    grid_enc_kernel<0><<<blocksP, 256, 0, stream>>>(in, emb, out, B);
    grid_enc_kernel<8><<<blocksP, 256, 0, stream>>>(in, emb, out, B);
  }
}

// Round 7
// 706.496 us; speedup vs baseline: 1.0022x; 1.0022x over previous
//
#include <hip/hip_runtime.h>
#include <cstdint>

// InstantNGP hash-grid encoder, MI355X, v5 (resubmit; R5/R6 were infra fails).
// D=3, L=16, F=2, N_MIN=16, PLS=2 -> scale_l = 16*2^l - 1, res_l = 16*2^l.
// Levels 0..2 dense (mod provably no-op), levels 3..15 hashed, hmap=2^19.
// v4 lessons (rocprof): mega fusion works (38 us/level); cost model: hashed
// levels average 6 distinct 64B lines/point (odd-i0 corner pair needs 2
// lines), ~80M random line-requests total at ~150 G req/s chip-wide service
// = 533 us ~= measured 536 -> mega is AT the request-service wall. The
// no-LDS transpose regressed to ~172 us because its load lanes were NOT
// contiguous (8 lanes x 8B on rows 16MB apart -> per-lane line requests).
// v5: wave-local shuffle transpose: each wave owns 8 points x 16 rows (1KB);
// load = 16 full 64B lines (lanes 4k..4k+3 contiguous), in-register
// transpose via 8 ds_bpermute (__shfl), store = 1KB contiguous. No LDS
// allocation, no barriers, full occupancy.

static constexpr uint32_t kOff[17] = {
    0u, 4913u, 40850u, 315475u, 839763u, 1364051u, 1888339u, 2412627u,
    2936915u, 3461203u, 3985491u, 4509779u, 5034067u, 5558355u, 6082643u,
    6606931u, 7131219u};
// kOff[l] for l>=3 is 315475 + (l-3)*524288 (each hashed table 2^19 entries).

static constexpr uint32_t P1 = 2654435761u;
static constexpr uint32_t P2 = 805459861u;

// 16B vector with 8B alignment (table pair-loads never straddle a 64B line).
typedef float f4a8 __attribute__((ext_vector_type(4), aligned(8)));
typedef float v2f __attribute__((ext_vector_type(2)));
typedef float v4f __attribute__((ext_vector_type(4)));

__device__ __forceinline__ float2 ntload2(const float2* p) {
  v2f t = __builtin_nontemporal_load((const v2f*)p);
  return make_float2(t[0], t[1]);
}
__device__ __forceinline__ float4 ntload4(const float4* p) {
  v4f t = __builtin_nontemporal_load((const v4f*)p);
  return make_float4(t[0], t[1], t[2], t[3]);
}
__device__ __forceinline__ void ntstore2(float2* p, float a, float b) {
  v2f t;
  t[0] = a;
  t[1] = b;
  __builtin_nontemporal_store(t, (v2f*)p);
}
__device__ __forceinline__ void ntstore4(float4* p, float a, float b, float c,
                                         float d) {
  v4f t;
  t[0] = a;
  t[1] = b;
  t[2] = c;
  t[3] = d;
  __builtin_nontemporal_store(t, (v4f*)p);
}

__device__ __forceinline__ float to_unit(float v) {
  // x = (in + 1) / 2 ; *0.5 exact, matches reference
  return __fmul_rn(__fadd_rn(v, 1.0f), 0.5f);
}

// pos = x*scale + 0.5 with separate mul/add rounding (match reference).
__device__ __forceinline__ void pos_decomp_rt(float x0, float x1, float x2,
                                              float scale, uint32_t& i0,
                                              uint32_t& i1, uint32_t& i2,
                                              float& f0, float& f1, float& f2) {
  float p0 = __fadd_rn(__fmul_rn(x0, scale), 0.5f);
  float p1 = __fadd_rn(__fmul_rn(x1, scale), 0.5f);
  float p2 = __fadd_rn(__fmul_rn(x2, scale), 0.5f);
  float g0 = floorf(p0), g1 = floorf(p1), g2 = floorf(p2);
  f0 = __fsub_rn(p0, g0);
  f1 = __fsub_rn(p1, g1);
  f2 = __fsub_rn(p2, g2);
  i0 = (uint32_t)g0;
  i1 = (uint32_t)g1;
  i2 = (uint32_t)g2;
}

// Hashed level, runtime scale/table-base (identical for all levels >= 3:
// mask 2^19-1, primes fixed). Reference corner order and fp op order kept.
__device__ __forceinline__ void hashed_accum_rt(float x0, float x1, float x2,
                                                float scale,
                                                const float2* __restrict__ t2,
                                                float& A0, float& A1) {
  constexpr uint32_t mask = 0x7FFFFu;  // hmap = 2^19
  uint32_t i0, i1, i2;
  float f0, f1, f2;
  pos_decomp_rt(x0, x1, x2, scale, i0, i1, i2, f0, f1, f2);

  const float w0l = __fsub_rn(1.0f, f0), w0h = f0;
  const float w1v[2] = {__fsub_rn(1.0f, f1), f1};
  const float w2v[2] = {__fsub_rn(1.0f, f2), f2};
  uint32_t h1v[2], h2v[2];
  h1v[0] = i1 * P1;
  h1v[1] = h1v[0] + P1;
  h2v[0] = i2 * P2;
  h2v[1] = h2v[0] + P2;

  const bool odd = (i0 & 1u) != 0u;
  float acc0 = A0, acc1 = A1;
#pragma unroll
  for (int b2 = 0; b2 < 2; ++b2) {
#pragma unroll
    for (int b1 = 0; b1 < 2; ++b1) {
      const uint32_t ex = h1v[b1] ^ h2v[b2];
      const uint32_t ilo = (i0 ^ ex) & mask;
      // one 16B load covers entries {ilo&~1, ilo|1}
      const f4a8 v = *(const f4a8*)(t2 + (ilo & ~1u));
      const bool hs = (ilo & 1u) != 0u;
      float eL0 = hs ? v.z : v.x;
      float eL1 = hs ? v.w : v.y;
      float eH0 = hs ? v.x : v.z;  // valid when i0 even (ihi == ilo^1)
      float eH1 = hs ? v.y : v.w;
      if (odd) {
        const uint32_t ihi = ((i0 + 1u) ^ ex) & mask;
        const float2 e = t2[ihi];
        eH0 = e.x;
        eH1 = e.y;
      }
      const float wl = __fmul_rn(__fmul_rn(w0l, w1v[b1]), w2v[b2]);
      const float wh = __fmul_rn(__fmul_rn(w0h, w1v[b1]), w2v[b2]);
      acc0 = __fadd_rn(acc0, __fmul_rn(wl, eL0));
      acc1 = __fadd_rn(acc1, __fmul_rn(wl, eL1));
      acc0 = __fadd_rn(acc0, __fmul_rn(wh, eH0));
      acc1 = __fadd_rn(acc1, __fmul_rn(wh, eH1));
    }
  }
  A0 = acc0;
  A1 = acc1;
}

// Dense level (LV < 3): corner pair always adjacent -> one 16B load.
template <int LV>
__device__ __forceinline__ void dense_accum(float x0, float x1, float x2,
                                            const float* __restrict__ embf,
                                            float& A0, float& A1) {
  static_assert(LV < 3, "");
  constexpr uint32_t res = 16u << LV;
  constexpr uint32_t off = kOff[LV];
  constexpr uint32_t s1 = res + 1u, s2 = s1 * s1;
  constexpr float scale = (float)res - 1.0f;
  uint32_t i0, i1, i2;
  float f0, f1, f2;
  pos_decomp_rt(x0, x1, x2, scale, i0, i1, i2, f0, f1, f2);

  const float w0l = __fsub_rn(1.0f, f0), w0h = f0;
  const float w1v[2] = {__fsub_rn(1.0f, f1), f1};
  const float w2v[2] = {__fsub_rn(1.0f, f2), f2};
  const uint32_t base = i0 + i1 * s1 + i2 * s2;
  const float2* t2 = (const float2*)embf + off;

  float acc0 = A0, acc1 = A1;
#pragma unroll
  for (int b2 = 0; b2 < 2; ++b2) {
#pragma unroll
    for (int b1 = 0; b1 < 2; ++b1) {
      const uint32_t idx = base + (b1 ? s1 : 0u) + (b2 ? s2 : 0u);
      const f4a8 v = *(const f4a8*)(t2 + idx);  // {e[idx], e[idx+1]}
      const float wl = __fmul_rn(__fmul_rn(w0l, w1v[b1]), w2v[b2]);
      const float wh = __fmul_rn(__fmul_rn(w0h, w1v[b1]), w2v[b2]);
      acc0 = __fadd_rn(acc0, __fmul_rn(wl, v.x));
      acc1 = __fadd_rn(acc1, __fmul_rn(wl, v.y));
      acc0 = __fadd_rn(acc0, __fmul_rn(wh, v.z));
      acc1 = __fadd_rn(acc1, __fmul_rn(wh, v.w));
    }
  }
  A0 = acc0;
  A1 = acc1;
}

// --------------------------- mega gather kernel ---------------------------
// zone 0: dense levels 0..2; zone z in 1..13: hashed level z+2.
// 2 points/thread; ws layout [16][B] float2.

__global__ __launch_bounds__(256) void mega_kernel(
    const float* __restrict__ in, const float* __restrict__ embf,
    float2* __restrict__ ws, int B, int NB) {
  const int zone = blockIdx.x / NB;
  const int q = (blockIdx.x - zone * NB) * 256 + threadIdx.x;
  const int p0 = q << 1;
  if (p0 >= B) return;
  const bool hasB = (p0 + 1) < B;

  float xA0, xA1, xA2, xB0 = 0.f, xB1 = 0.f, xB2 = 0.f;
  if (hasB) {
    const float2* in2 = (const float2*)in;
    const size_t b3 = (size_t)q * 3;
    const float2 u0 = ntload2(in2 + b3);
    const float2 u1 = ntload2(in2 + b3 + 1);
    const float2 u2 = ntload2(in2 + b3 + 2);
    xA0 = to_unit(u0.x);
    xA1 = to_unit(u0.y);
    xA2 = to_unit(u1.x);
    xB0 = to_unit(u1.y);
    xB1 = to_unit(u2.x);
    xB2 = to_unit(u2.y);
  } else {  // last point when B odd: avoid reading past in[]
    xA0 = to_unit(in[(size_t)p0 * 3 + 0]);
    xA1 = to_unit(in[(size_t)p0 * 3 + 1]);
    xA2 = to_unit(in[(size_t)p0 * 3 + 2]);
  }
  const bool pair4 = hasB && ((B & 1) == 0);  // 16B-aligned float4 ws store

  if (zone == 0) {
    float a0, a1, b0, b1;
#define DO_DENSE(LV)                                              \
  a0 = a1 = b0 = b1 = 0.0f;                                       \
  dense_accum<LV>(xA0, xA1, xA2, embf, a0, a1);                   \
  if (hasB) dense_accum<LV>(xB0, xB1, xB2, embf, b0, b1);         \
  {                                                               \
    float2* wsl = ws + (size_t)LV * B;                            \
    if (pair4)                                                    \
      ntstore4((float4*)(wsl + p0), a0, a1, b0, b1);              \
    else {                                                        \
      ntstore2(wsl + p0, a0, a1);                                 \
      if (hasB) ntstore2(wsl + p0 + 1, b0, b1);                   \
    }                                                             \
  }
    DO_DENSE(0)
    DO_DENSE(1)
    DO_DENSE(2)
#undef DO_DENSE
  } else {
    const int level = zone + 2;  // 3..15
    const float scale = (float)(int)((16u << level) - 1u);
    const float2* t2 =
        (const float2*)embf + (315475u + (uint32_t)(level - 3) * 524288u);
    float2* wsl = ws + (size_t)level * B;

    float a0 = 0.0f, a1 = 0.0f;
    hashed_accum_rt(xA0, xA1, xA2, scale, t2, a0, a1);
    if (pair4) {
      float b0 = 0.0f, b1 = 0.0f;
      hashed_accum_rt(xB0, xB1, xB2, scale, t2, b0, b1);
      ntstore4((float4*)(wsl + p0), a0, a1, b0, b1);
    } else {
      ntstore2(wsl + p0, a0, a1);
      if (hasB) {
        float b0 = 0.0f, b1 = 0.0f;
        hashed_accum_rt(xB0, xB1, xB2, scale, t2, b0, b1);
        ntstore2(wsl + p0 + 1, b0, b1);
      }
    }
  }
}

// ----------------------- wave-shuffle transpose -----------------------
// Each wave owns 8 points x 16 rows (1 KB). Load: lane l reads one float4
// at row l>>2, point-pair l&3 -> lanes 4k..4k+3 cover a full 64B line (16
// line requests/wave). In-register transpose via 8 ds_bpermute. Store: lane
// l writes out4[p0*8+l] -> contiguous 1 KB. Requires B % 8 == 0 (guaranteed
// by launcher; generic fallback otherwise).

__global__ __launch_bounds__(256) void wave_transpose_kernel(
    const float4* __restrict__ ws4, float4* __restrict__ out4, int B) {
  const int lane = (int)(threadIdx.x & 63u);
  const size_t wave = ((size_t)blockIdx.x * 256 + threadIdx.x) >> 6;
  const size_t p0 = wave * 8;
  if (p0 >= (size_t)B) return;

  const int r = lane >> 2;       // row 0..15
  const int c = lane & 3;        // point-pair 0..3
  const size_t rowstride4 = (size_t)(B >> 1);  // float4 per ws row
  const float4 v = ntload4(ws4 + (size_t)r * rowstride4 + (p0 >> 1) + c);

  const int pt = lane >> 3;  // 0..7 point within granule
  const int j = lane & 7;    // out quad = rows {2j, 2j+1}
  const int s0 = 8 * j + (pt >> 1);  // lane holding row 2j, pts {2(pt>>1),+1}
  const int s1 = s0 + 4;             // same for row 2j+1
  float4 A, Bv;
  A.x = __shfl(v.x, s0);
  A.y = __shfl(v.y, s0);
  A.z = __shfl(v.z, s0);
  A.w = __shfl(v.w, s0);
  Bv.x = __shfl(v.x, s1);
  Bv.y = __shfl(v.y, s1);
  Bv.z = __shfl(v.z, s1);
  Bv.w = __shfl(v.w, s1);
  const bool hi = (pt & 1) != 0;
  const float o0 = hi ? A.z : A.x;
  const float o1 = hi ? A.w : A.y;
  const float o2 = hi ? Bv.z : Bv.x;
  const float o3 = hi ? Bv.w : Bv.y;
  ntstore4(out4 + p0 * 8 + lane, o0, o1, o2, o3);
}

// Generic transpose (any B): thread -> one out float4, scalar float2 loads.
__global__ __launch_bounds__(256) void transpose_generic_kernel(
    const float2* __restrict__ ws, float4* __restrict__ out4, size_t n4,
    int B) {
  const size_t g = (size_t)blockIdx.x * 256 + threadIdx.x;
  if (g >= n4) return;
  const int p = (int)(g >> 3);
  const int j = (int)(g & 7);
  const float2 e0 = ntload2(ws + (size_t)(2 * j) * B + p);
  const float2 e1 = ntload2(ws + (size_t)(2 * j + 1) * B + p);
  ntstore4(out4 + g, e0.x, e0.y, e1.x, e1.y);
}

// ---------------- fallback (ws too small): 8 levels/kernel ----------------

template <int LV>
__device__ __forceinline__ void any_accum(float x0, float x1, float x2,
                                          const float* __restrict__ embf,
                                          float& A0, float& A1) {
  if constexpr (LV < 3) {
    dense_accum<LV>(x0, x1, x2, embf, A0, A1);
  } else {
    constexpr float scale = (float)(16u << LV) - 1.0f;
    const float2* t2 = (const float2*)embf + kOff[LV];
    hashed_accum_rt(x0, x1, x2, scale, t2, A0, A1);
  }
}

template <int LBASE>
__global__ __launch_bounds__(256) void grid_enc_kernel(
    const float* __restrict__ in, const float* __restrict__ embf,
    float* __restrict__ out, int B) {
  const int p = blockIdx.x * 256 + threadIdx.x;
  if (p >= B) return;
  const float x0 = to_unit(in[(size_t)p * 3 + 0]);
  const float x1 = to_unit(in[(size_t)p * 3 + 1]);
  const float x2 = to_unit(in[(size_t)p * 3 + 2]);

  float a[16];
#pragma unroll
  for (int i = 0; i < 16; ++i) a[i] = 0.0f;

  any_accum<LBASE + 0>(x0, x1, x2, embf, a[0], a[1]);
  any_accum<LBASE + 1>(x0, x1, x2, embf, a[2], a[3]);
  any_accum<LBASE + 2>(x0, x1, x2, embf, a[4], a[5]);
  any_accum<LBASE + 3>(x0, x1, x2, embf, a[6], a[7]);
  any_accum<LBASE + 4>(x0, x1, x2, embf, a[8], a[9]);
  any_accum<LBASE + 5>(x0, x1, x2, embf, a[10], a[11]);
  any_accum<LBASE + 6>(x0, x1, x2, embf, a[12], a[13]);
  any_accum<LBASE + 7>(x0, x1, x2, embf, a[14], a[15]);

  float4* __restrict__ o = (float4*)(out + (size_t)p * 32 + LBASE * 2);
  o[0] = make_float4(a[0], a[1], a[2], a[3]);
  o[1] = make_float4(a[4], a[5], a[6], a[7]);
  o[2] = make_float4(a[8], a[9], a[10], a[11]);
  o[3] = make_float4(a[12], a[13], a[14], a[15]);
}

extern "C" void kernel_launch(void* const* d_in, const int* in_sizes, int n_in,
                              void* d_out, int out_size, void* d_ws,
                              size_t ws_size, hipStream_t stream) {
  const float* in = (const float*)d_in[0];
  const float* emb = (const float*)d_in[1];
  float* out = (float*)d_out;
  const int B = in_sizes[0] / 3;
  const size_t ws_needed = (size_t)16 * (size_t)B * sizeof(float2);

  if (ws_size >= ws_needed) {
    float2* ws = (float2*)d_ws;
    const int NB = ((B + 1) / 2 + 255) / 256;  // blocks per zone
    mega_kernel<<<NB * 14, 256, 0, stream>>>(in, emb, ws, B, NB);
    if ((B & 7) == 0) {
      const int waves = B / 8;
      const int tb = (waves + 3) / 4;  // 4 waves per 256-thread block
      wave_transpose_kernel<<<tb, 256, 0, stream>>>((const float4*)ws,
                                                    (float4*)out, B);
    } else {
      const size_t n4 = (size_t)B * 8;
      const int tb = (int)((n4 + 255) / 256);
      transpose_generic_kernel<<<tb, 256, 0, stream>>>(ws, (float4*)out, n4,
                                                       B);
    }
  } else {
    const int blocksP = (B + 255) / 256;
    grid_enc_kernel<0><<<blocksP, 256, 0, stream>>>(in, emb, out, B);
    grid_enc_kernel<8><<<blocksP, 256, 0, stream>>>(in, emb, out, B);
  }
}